// Round 2
// baseline (691.459 us; speedup 1.0000x reference)
//
#include <hip/hip_runtime.h>

// Multiresolution hash-grid embedding (Instant-NGP style).
// 1 thread = 1 point; 16 levels fully unrolled with compile-time resolutions;
// 8 random float2 gathers per level; 32-float accumulator -> one full 128B
// row written with nontemporal dwordx4 stores.

#define TSIZE (1u << 19)
#define HMASK (TSIZE - 1u)
#define P1 2654435761u
#define P2 805459861u

typedef float f32x4 __attribute__((ext_vector_type(4)));

__global__ __launch_bounds__(256) void hashgrid_kernel(
    const float* __restrict__ x,
    const float* __restrict__ tables,
    float* __restrict__ out)
{
    const int p = blockIdx.x * 256 + threadIdx.x;

    // x in [0,1); shift by -BOX_MIN = +1
    const float px = x[3 * p + 0] + 1.0f;
    const float py = x[3 * p + 1] + 1.0f;
    const float pz = x[3 * p + 2] + 1.0f;

    float acc[32];

    // floor(16 * b^i), b = 2^(1/3)  (matches numpy float64 evaluation)
    constexpr float RES[16] = {16.f, 20.f, 25.f, 32.f, 40.f, 50.f, 64.f, 80.f,
                               101.f, 128.f, 161.f, 203.f, 256.f, 322.f, 406.f, 512.f};

#pragma unroll
    for (int l = 0; l < 16; ++l) {
        const float r     = RES[l];
        const float halfr = 0.5f * r;     // 1/grid (grid = 2/r); exact for these r

        const float fx = px * halfr;
        const float fy = py * halfr;
        const float fz = pz * halfr;

        const float bx = floorf(fx);
        const float by = floorf(fy);
        const float bz = floorf(fz);

        // interpolation weights; ±1ulp floor flips land on shared faces where
        // trilerp is continuous -> error << threshold
        const float wx = fx - bx;
        const float wy = fy - by;
        const float wz = fz - bz;

        const unsigned ix0 = (unsigned)(int)bx;           // * prime 1
        const unsigned iy0 = (unsigned)(int)by * P1;
        const unsigned iz0 = (unsigned)(int)bz * P2;
        const unsigned ix1 = ix0 + 1u;
        const unsigned iy1 = iy0 + P1;
        const unsigned iz1 = iz0 + P2;

        const float2* __restrict__ tab = (const float2*)tables + (size_t)l * TSIZE;

        const float2 v000 = tab[(ix0 ^ iy0 ^ iz0) & HMASK];
        const float2 v001 = tab[(ix0 ^ iy0 ^ iz1) & HMASK];
        const float2 v010 = tab[(ix0 ^ iy1 ^ iz0) & HMASK];
        const float2 v011 = tab[(ix0 ^ iy1 ^ iz1) & HMASK];
        const float2 v100 = tab[(ix1 ^ iy0 ^ iz0) & HMASK];
        const float2 v101 = tab[(ix1 ^ iy0 ^ iz1) & HMASK];
        const float2 v110 = tab[(ix1 ^ iy1 ^ iz0) & HMASK];
        const float2 v111 = tab[(ix1 ^ iy1 ^ iz1) & HMASK];

        // lerp over x
        const float c00a = v000.x + wx * (v100.x - v000.x);
        const float c00b = v000.y + wx * (v100.y - v000.y);
        const float c01a = v001.x + wx * (v101.x - v001.x);
        const float c01b = v001.y + wx * (v101.y - v001.y);
        const float c10a = v010.x + wx * (v110.x - v010.x);
        const float c10b = v010.y + wx * (v110.y - v010.y);
        const float c11a = v011.x + wx * (v111.x - v011.x);
        const float c11b = v011.y + wx * (v111.y - v011.y);
        // lerp over y
        const float c0a = c00a + wy * (c10a - c00a);
        const float c0b = c00b + wy * (c10b - c00b);
        const float c1a = c01a + wy * (c11a - c01a);
        const float c1b = c01b + wy * (c11b - c01b);
        // lerp over z
        acc[2 * l + 0] = c0a + wz * (c1a - c0a);
        acc[2 * l + 1] = c0b + wz * (c1b - c0b);
    }

    f32x4* orow = (f32x4*)(out + (size_t)p * 32);
#pragma unroll
    for (int i = 0; i < 8; ++i) {
        f32x4 v = { acc[4 * i + 0], acc[4 * i + 1], acc[4 * i + 2], acc[4 * i + 3] };
        __builtin_nontemporal_store(v, orow + i);
    }
}

extern "C" void kernel_launch(void* const* d_in, const int* in_sizes, int n_in,
                              void* d_out, int out_size, void* d_ws, size_t ws_size,
                              hipStream_t stream) {
    const float* x      = (const float*)d_in[0];
    const float* tables = (const float*)d_in[1];
    float* out          = (float*)d_out;

    const int npoints = in_sizes[0] / 3;           // 1048576
    dim3 block(256);
    dim3 grid((npoints + 255) / 256);              // 4096 blocks

    hipLaunchKernelGGL(hashgrid_kernel, grid, block, 0, stream, x, tables, out);
}

// Round 3
// 633.057 us; speedup vs baseline: 1.0923x; 1.0923x over previous
//
#include <hip/hip_runtime.h>

// Multiresolution hash-grid embedding (Instant-NGP style).
// 1 thread = 1 point. Levels processed in groups of 4: all 32 independent
// float2 gathers of a group are issued before any lerp consumes them
// (memory-level parallelism to cover L2/L3 gather latency).
// Output row (128 B) written with regular cached dwordx4 stores so L2
// merges them into full lines (nontemporal write-through caused 2.5x
// write amplification in round 2).

#define TSIZE (1u << 19)
#define HMASK (TSIZE - 1u)
#define P1 2654435761u
#define P2 805459861u

typedef float f32x4 __attribute__((ext_vector_type(4)));

__global__ __launch_bounds__(256) void hashgrid_kernel(
    const float* __restrict__ x,
    const float* __restrict__ tables,
    float* __restrict__ out)
{
    const int p = blockIdx.x * 256 + threadIdx.x;

    // x in [0,1); shift by -BOX_MIN = +1
    const float px = x[3 * p + 0] + 1.0f;
    const float py = x[3 * p + 1] + 1.0f;
    const float pz = x[3 * p + 2] + 1.0f;

    float acc[32];

    // floor(16 * b^i), b = 2^(1/3)  (matches numpy float64 evaluation)
    constexpr float RES[16] = {16.f, 20.f, 25.f, 32.f, 40.f, 50.f, 64.f, 80.f,
                               101.f, 128.f, 161.f, 203.f, 256.f, 322.f, 406.f, 512.f};

    const float2* __restrict__ tab = (const float2*)tables;

#pragma unroll
    for (int g = 0; g < 4; ++g) {
        float2 v[4][8];
        float wx[4], wy[4], wz[4];

        // Phase 1: compute addresses + issue all 32 gathers for this group
#pragma unroll
        for (int i = 0; i < 4; ++i) {
            const int l = g * 4 + i;
            const float halfr = 0.5f * RES[l];   // 1/grid; exact for these r

            const float fx = px * halfr;
            const float fy = py * halfr;
            const float fz = pz * halfr;

            const float bx = floorf(fx);
            const float by = floorf(fy);
            const float bz = floorf(fz);

            wx[i] = fx - bx;
            wy[i] = fy - by;
            wz[i] = fz - bz;

            const unsigned ix0 = (unsigned)(int)bx;           // * prime 1
            const unsigned iy0 = (unsigned)(int)by * P1;
            const unsigned iz0 = (unsigned)(int)bz * P2;
            const unsigned ix1 = ix0 + 1u;
            const unsigned iy1 = iy0 + P1;
            const unsigned iz1 = iz0 + P2;

            const unsigned base = (unsigned)l * TSIZE;
            v[i][0] = tab[base + ((ix0 ^ iy0 ^ iz0) & HMASK)];
            v[i][1] = tab[base + ((ix0 ^ iy0 ^ iz1) & HMASK)];
            v[i][2] = tab[base + ((ix0 ^ iy1 ^ iz0) & HMASK)];
            v[i][3] = tab[base + ((ix0 ^ iy1 ^ iz1) & HMASK)];
            v[i][4] = tab[base + ((ix1 ^ iy0 ^ iz0) & HMASK)];
            v[i][5] = tab[base + ((ix1 ^ iy0 ^ iz1) & HMASK)];
            v[i][6] = tab[base + ((ix1 ^ iy1 ^ iz0) & HMASK)];
            v[i][7] = tab[base + ((ix1 ^ iy1 ^ iz1) & HMASK)];
        }

        // Phase 2: trilinear interpolation for the 4 levels
#pragma unroll
        for (int i = 0; i < 4; ++i) {
            const int l = g * 4 + i;
            const float wxi = wx[i], wyi = wy[i], wzi = wz[i];

            const float c00a = v[i][0].x + wxi * (v[i][4].x - v[i][0].x);
            const float c00b = v[i][0].y + wxi * (v[i][4].y - v[i][0].y);
            const float c01a = v[i][1].x + wxi * (v[i][5].x - v[i][1].x);
            const float c01b = v[i][1].y + wxi * (v[i][5].y - v[i][1].y);
            const float c10a = v[i][2].x + wxi * (v[i][6].x - v[i][2].x);
            const float c10b = v[i][2].y + wxi * (v[i][6].y - v[i][2].y);
            const float c11a = v[i][3].x + wxi * (v[i][7].x - v[i][3].x);
            const float c11b = v[i][3].y + wxi * (v[i][7].y - v[i][3].y);

            const float c0a = c00a + wyi * (c10a - c00a);
            const float c0b = c00b + wyi * (c10b - c00b);
            const float c1a = c01a + wyi * (c11a - c01a);
            const float c1b = c01b + wyi * (c11b - c01b);

            acc[2 * l + 0] = c0a + wzi * (c1a - c0a);
            acc[2 * l + 1] = c0b + wzi * (c1b - c0b);
        }
    }

    f32x4* orow = (f32x4*)(out + (size_t)p * 32);
#pragma unroll
    for (int i = 0; i < 8; ++i) {
        f32x4 v = { acc[4 * i + 0], acc[4 * i + 1], acc[4 * i + 2], acc[4 * i + 3] };
        orow[i] = v;   // cached store: L2 merges partials into full lines
    }
}

extern "C" void kernel_launch(void* const* d_in, const int* in_sizes, int n_in,
                              void* d_out, int out_size, void* d_ws, size_t ws_size,
                              hipStream_t stream) {
    const float* x      = (const float*)d_in[0];
    const float* tables = (const float*)d_in[1];
    float* out          = (float*)d_out;

    const int npoints = in_sizes[0] / 3;           // 1048576
    dim3 block(256);
    dim3 grid((npoints + 255) / 256);              // 4096 blocks

    hipLaunchKernelGGL(hashgrid_kernel, grid, block, 0, stream, x, tables, out);
}

// Round 4
// 564.152 us; speedup vs baseline: 1.2257x; 1.1221x over previous
//
#include <hip/hip_runtime.h>

// Level-phased multiresolution hash-grid embedding.
// Round-3 diagnosis: per-thread all-16-levels walk thrashes each XCD's 4 MB
// L2 across ~9 fine-level 4 MB tables (FETCH 1.24 GB, ~2.3 cyc/lane-gather).
// Fix: Kernel A processes ONE level per block with level as the slow blockIdx
// index, so co-resident blocks share a single 4 MB table per XCD L2.
// Results land in a level-major ws (nontemporal full-line stores keep the
// stream out of L2); Kernel B transposes to the point-major output layout.

#define TSIZE (1u << 19)
#define HMASK (TSIZE - 1u)
#define P1 2654435761u
#define P2 805459861u

typedef float f32x4 __attribute__((ext_vector_type(4)));
typedef float f32x2 __attribute__((ext_vector_type(2)));

__constant__ float RES_C[16] = {16.f, 20.f, 25.f, 32.f, 40.f, 50.f, 64.f, 80.f,
                                101.f, 128.f, 161.f, 203.f, 256.f, 322.f, 406.f, 512.f};

// ---------------- Kernel A: one level per block, 2 points per thread ----------------
__global__ __launch_bounds__(256) void gather_level_kernel(
    const float* __restrict__ x,
    const float* __restrict__ tables,
    f32x2* __restrict__ ws,          // [16][npoints] float2
    int npoints, int levelShift)
{
    const int level = blockIdx.x >> levelShift;              // slow index -> phases
    const int chunk = blockIdx.x & ((1 << levelShift) - 1);
    const float halfr = 0.5f * RES_C[level];                 // 1/grid, exact

    const float2* __restrict__ tab = (const float2*)tables + (size_t)level * TSIZE;
    f32x2* __restrict__ wrow = ws + (size_t)level * npoints;

#pragma unroll
    for (int q = 0; q < 2; ++q) {
        const int p = chunk * 512 + q * 256 + threadIdx.x;
        if (p >= npoints) break;

        const float fx = (x[3 * p + 0] + 1.0f) * halfr;
        const float fy = (x[3 * p + 1] + 1.0f) * halfr;
        const float fz = (x[3 * p + 2] + 1.0f) * halfr;

        const float bx = floorf(fx);
        const float by = floorf(fy);
        const float bz = floorf(fz);

        const float wx = fx - bx;
        const float wy = fy - by;
        const float wz = fz - bz;

        const unsigned ix0 = (unsigned)(int)bx;              // * prime 1
        const unsigned iy0 = (unsigned)(int)by * P1;
        const unsigned iz0 = (unsigned)(int)bz * P2;
        const unsigned ix1 = ix0 + 1u;
        const unsigned iy1 = iy0 + P1;
        const unsigned iz1 = iz0 + P2;

        const float2 v000 = tab[(ix0 ^ iy0 ^ iz0) & HMASK];
        const float2 v001 = tab[(ix0 ^ iy0 ^ iz1) & HMASK];
        const float2 v010 = tab[(ix0 ^ iy1 ^ iz0) & HMASK];
        const float2 v011 = tab[(ix0 ^ iy1 ^ iz1) & HMASK];
        const float2 v100 = tab[(ix1 ^ iy0 ^ iz0) & HMASK];
        const float2 v101 = tab[(ix1 ^ iy0 ^ iz1) & HMASK];
        const float2 v110 = tab[(ix1 ^ iy1 ^ iz0) & HMASK];
        const float2 v111 = tab[(ix1 ^ iy1 ^ iz1) & HMASK];

        const float c00a = v000.x + wx * (v100.x - v000.x);
        const float c00b = v000.y + wx * (v100.y - v000.y);
        const float c01a = v001.x + wx * (v101.x - v001.x);
        const float c01b = v001.y + wx * (v101.y - v001.y);
        const float c10a = v010.x + wx * (v110.x - v010.x);
        const float c10b = v010.y + wx * (v110.y - v010.y);
        const float c11a = v011.x + wx * (v111.x - v011.x);
        const float c11b = v011.y + wx * (v111.y - v011.y);

        const float c0a = c00a + wy * (c10a - c00a);
        const float c0b = c00b + wy * (c10b - c00b);
        const float c1a = c01a + wy * (c11a - c01a);
        const float c1b = c01b + wy * (c11b - c01b);

        f32x2 r = { c0a + wz * (c1a - c0a), c0b + wz * (c1b - c0b) };
        // 64 lanes x 8 B contiguous = full 64 B lines per instruction:
        // nontemporal is safe here and keeps the ws stream from evicting
        // the hot table in L2.
        __builtin_nontemporal_store(r, wrow + p);
    }
}

// ---------------- Kernel B: transpose [16][N][2] -> [N][32] ----------------
__global__ __launch_bounds__(256) void transpose_kernel(
    const f32x2* __restrict__ ws,
    float* __restrict__ out,
    int npoints)
{
    const int p = blockIdx.x * 256 + threadIdx.x;
    if (p >= npoints) return;

    f32x2 v[16];
#pragma unroll
    for (int l = 0; l < 16; ++l)
        v[l] = __builtin_nontemporal_load(ws + (size_t)l * npoints + p);

    f32x4* orow = (f32x4*)(out + (size_t)p * 32);
#pragma unroll
    for (int i = 0; i < 8; ++i) {
        f32x4 q = { v[2 * i].x, v[2 * i].y, v[2 * i + 1].x, v[2 * i + 1].y };
        orow[i] = q;   // cached: L2 merges the strided 16 B partials (round-3 win)
    }
}

// ---------------- Fallback (round-3 kernel) if ws too small ----------------
__global__ __launch_bounds__(256) void hashgrid_fallback_kernel(
    const float* __restrict__ x,
    const float* __restrict__ tables,
    float* __restrict__ out)
{
    const int p = blockIdx.x * 256 + threadIdx.x;

    const float px = x[3 * p + 0] + 1.0f;
    const float py = x[3 * p + 1] + 1.0f;
    const float pz = x[3 * p + 2] + 1.0f;

    float acc[32];
    const float2* __restrict__ tab = (const float2*)tables;

#pragma unroll
    for (int l = 0; l < 16; ++l) {
        const float halfr = 0.5f * RES_C[l];
        const float fx = px * halfr, fy = py * halfr, fz = pz * halfr;
        const float bx = floorf(fx), by = floorf(fy), bz = floorf(fz);
        const float wx = fx - bx, wy = fy - by, wz = fz - bz;

        const unsigned ix0 = (unsigned)(int)bx;
        const unsigned iy0 = (unsigned)(int)by * P1;
        const unsigned iz0 = (unsigned)(int)bz * P2;
        const unsigned ix1 = ix0 + 1u, iy1 = iy0 + P1, iz1 = iz0 + P2;
        const unsigned base = (unsigned)l * TSIZE;

        const float2 v000 = tab[base + ((ix0 ^ iy0 ^ iz0) & HMASK)];
        const float2 v001 = tab[base + ((ix0 ^ iy0 ^ iz1) & HMASK)];
        const float2 v010 = tab[base + ((ix0 ^ iy1 ^ iz0) & HMASK)];
        const float2 v011 = tab[base + ((ix0 ^ iy1 ^ iz1) & HMASK)];
        const float2 v100 = tab[base + ((ix1 ^ iy0 ^ iz0) & HMASK)];
        const float2 v101 = tab[base + ((ix1 ^ iy0 ^ iz1) & HMASK)];
        const float2 v110 = tab[base + ((ix1 ^ iy1 ^ iz0) & HMASK)];
        const float2 v111 = tab[base + ((ix1 ^ iy1 ^ iz1) & HMASK)];

        const float c00a = v000.x + wx * (v100.x - v000.x);
        const float c00b = v000.y + wx * (v100.y - v000.y);
        const float c01a = v001.x + wx * (v101.x - v001.x);
        const float c01b = v001.y + wx * (v101.y - v001.y);
        const float c10a = v010.x + wx * (v110.x - v010.x);
        const float c10b = v010.y + wx * (v110.y - v010.y);
        const float c11a = v011.x + wx * (v111.x - v011.x);
        const float c11b = v011.y + wx * (v111.y - v011.y);

        const float c0a = c00a + wy * (c10a - c00a);
        const float c0b = c00b + wy * (c10b - c00b);
        const float c1a = c01a + wy * (c11a - c01a);
        const float c1b = c01b + wy * (c11b - c01b);

        acc[2 * l + 0] = c0a + wz * (c1a - c0a);
        acc[2 * l + 1] = c0b + wz * (c1b - c0b);
    }

    f32x4* orow = (f32x4*)(out + (size_t)p * 32);
#pragma unroll
    for (int i = 0; i < 8; ++i) {
        f32x4 v = { acc[4 * i + 0], acc[4 * i + 1], acc[4 * i + 2], acc[4 * i + 3] };
        orow[i] = v;
    }
}

extern "C" void kernel_launch(void* const* d_in, const int* in_sizes, int n_in,
                              void* d_out, int out_size, void* d_ws, size_t ws_size,
                              hipStream_t stream) {
    const float* x      = (const float*)d_in[0];
    const float* tables = (const float*)d_in[1];
    float* out          = (float*)d_out;

    const int npoints = in_sizes[0] / 3;                       // 1048576
    const size_t ws_needed = (size_t)16 * npoints * sizeof(float2);  // 128 MB

    if (ws_size >= ws_needed) {
        // chunks per level: ceil(npoints/512) rounded up to power of two
        int chunks = (npoints + 511) / 512;
        int levelShift = 0;
        while ((1 << levelShift) < chunks) ++levelShift;

        dim3 blockA(256);
        dim3 gridA(16 << levelShift);
        hipLaunchKernelGGL(gather_level_kernel, gridA, blockA, 0, stream,
                           x, tables, (f32x2*)d_ws, npoints, levelShift);

        dim3 blockB(256);
        dim3 gridB((npoints + 255) / 256);
        hipLaunchKernelGGL(transpose_kernel, gridB, blockB, 0, stream,
                           (const f32x2*)d_ws, out, npoints);
    } else {
        dim3 block(256);
        dim3 grid((npoints + 255) / 256);
        hipLaunchKernelGGL(hashgrid_fallback_kernel, grid, block, 0, stream,
                           x, tables, out);
    }
}